// Round 8
// baseline (222.032 us; speedup 1.0000x reference)
//
#include <hip/hip_runtime.h>

#define N_NODES 100000
#define N_EDGES 300000
#define N_GRAPHS 4000
#define CAP 32

typedef float f32x4 __attribute__((ext_vector_type(4)));
typedef float f32x16 __attribute__((ext_vector_type(16)));
typedef __bf16 bf16x8 __attribute__((ext_vector_type(8)));
typedef __bf16 bf16x4 __attribute__((ext_vector_type(4)));
typedef __bf16 bf16x2 __attribute__((ext_vector_type(2)));
typedef _Float16 f16x8 __attribute__((ext_vector_type(8)));

// ---------------- workspace layout (float offsets) ----------------
static const size_t OFF_XA    = 0;                                   // N*16
static const size_t OFF_AD4   = OFF_XA + (size_t)N_NODES * 16;       // N*4
static const size_t OFF_P2B   = OFF_AD4 + (size_t)N_NODES * 4;       // N*128 bf16
static const size_t OFF_ASAD2 = OFF_P2B + (size_t)N_NODES * 64;      // N*2
static const size_t OFF_WSB   = OFF_ASAD2 + (size_t)N_NODES * 2;     // 65536 bf16
static const size_t OFF_W1B   = OFF_WSB + 32768;                     // 8192 f16 = 4096 floats
static const size_t OFF_GST   = OFF_W1B + 4096;                      // gstart[4001]
static const size_t OFF_INT   = OFF_GST + 4096;                      // deg[N], bucket[N*CAP]

// k_pre block partition (256 threads each); deg zeroed by memset before launch
#define PRE_NODE_END 391   // ceil(100000/256)
#define PRE_PACKB_END 455  // +64: W2 pack
#define PRE_W1B_END 487    // +32: W1^T f16 pack [512][16]
#define PRE_GST_END 503    // +16: gstart
#define PRE_BKT_END 1675   // +1172: edge bucketing

// k_gemm 4-way chunk split (instrumentation: each dispatch ~18 us so the
// hidden k_pre / k_agg2pool surface in the rocprof top-5 with counters)
#define GEMM_BLOCKS 1563   // ceil(100000/64)
#define GEMM_CHUNK 391

__device__ __forceinline__ float lrelu(float x) { return x < 0.f ? 0.2f * x : x; }
__device__ __forceinline__ float elu(float x)   { return x > 0.f ? x : __expf(x) - 1.f; }

// Fat pre-kernel: node pack || W2 pack || W1^T pack || gstart || edge bucket
__global__ __launch_bounds__(256) void k_pre(
    const float* __restrict__ x, const float* __restrict__ W1,
    const float* __restrict__ a_src1, const float* __restrict__ a_dst1,
    const float* __restrict__ W2, const int* __restrict__ batch,
    const int* __restrict__ ei,
    float* __restrict__ xa, float* __restrict__ ad4,
    __bf16* __restrict__ wsB, _Float16* __restrict__ w1b,
    int* __restrict__ deg, int* __restrict__ bucket, int* __restrict__ gstart) {
    int b = blockIdx.x, tid = threadIdx.x;
    if (b < PRE_NODE_END) {
        __shared__ float wf[72];
        if (tid < 72) {
            int isd = tid / 36, r = tid % 36, k = r / 4, h = r % 4;
            const float* a = isd ? a_dst1 : a_src1;
            float s = 0.f;
            for (int c = 0; c < 128; c++) s += W1[k * 512 + h * 128 + c] * a[h * 128 + c];
            wf[tid] = s;
        }
        __syncthreads();
        int n = b * 256 + tid;
        if (n >= N_NODES) return;
        float xv[9];
#pragma unroll
        for (int k = 0; k < 9; k++) xv[k] = x[n * 9 + k];
        float as[4], ad[4];
#pragma unroll
        for (int h = 0; h < 4; h++) {
            float s = 0.f, d = 0.f;
#pragma unroll
            for (int k = 0; k < 9; k++) {
                s += xv[k] * wf[k * 4 + h];
                d += xv[k] * wf[36 + k * 4 + h];
            }
            as[h] = s; ad[h] = d;
        }
        f32x4* xp = (f32x4*)(xa + (size_t)n * 16);
        xp[0] = (f32x4){xv[0], xv[1], xv[2], xv[3]};
        xp[1] = (f32x4){xv[4], xv[5], xv[6], xv[7]};
        xp[2] = (f32x4){xv[8], as[0], as[1], as[2]};
        xp[3] = (f32x4){as[3], 0.f, 0.f, 0.f};
        *(f32x4*)(ad4 + (size_t)n * 4) = (f32x4){ad[0], ad[1], ad[2], ad[3]};
    } else if (b < PRE_PACKB_END) {
        int t = (b - PRE_NODE_END) * 256 + tid;
#pragma unroll
        for (int m = 0; m < 4; m++) {
            int idx = t * 4 + m;
            int k = idx >> 7, nn = idx & 127;
            wsB[(size_t)nn * 512 + k] = (__bf16)W2[(size_t)k * 128 + nn];
        }
    } else if (b < PRE_W1B_END) {
        int t = (b - PRE_PACKB_END) * 256 + tid;   // 0..8191
        int j = t >> 4, k = t & 15;
        w1b[t] = (k < 9) ? (_Float16)W1[(size_t)k * 512 + j] : (_Float16)0.f;
    } else if (b < PRE_GST_END) {
        int g = (b - PRE_W1B_END) * 256 + tid;
        if (g > N_GRAPHS) return;
        int lo = 0, hi = N_NODES;
        while (lo < hi) { int mid = (lo + hi) >> 1; if (batch[mid] < g) lo = mid + 1; else hi = mid; }
        gstart[g] = lo;
    } else {
        int e = (b - PRE_GST_END) * 256 + tid;
        if (e >= N_EDGES) return;
        int s = ei[e], d = ei[N_EDGES + e];
        int slot = atomicAdd(&deg[d], 1);
        if (slot < CAP) bucket[d * CAP + slot] = s;
    }
}

// Mega GEMM (r3 structure, best measured fused variant @69.5 us), chunked:
// m_off shifts the node-tile so the kernel can be launched as 4 dispatches
// of ~18 us each (instrumentation: surfaces hidden kernels in top-5).
__global__ __launch_bounds__(512, 6) void k_gemm(
    const float* __restrict__ xa, const float* __restrict__ ad4,
    const int* __restrict__ deg, const int* __restrict__ bucket,
    const _Float16* __restrict__ w1b, const float* __restrict__ b1,
    const __bf16* __restrict__ wsB,
    const float* __restrict__ a_src2, const float* __restrict__ a_dst2,
    __bf16* __restrict__ p2b, float* __restrict__ asad2, int m_off) {
    __shared__ __bf16 As[64 * 128];       // 16 KB, frag-major: tile t=rt*4+kc, lane*8
    __shared__ _Float16 AgF[4 * 64 * 24]; // 12 KB, [head][node][24] (k 0..15 used)
    float* red2 = (float*)AgF;            // 4 KB alias, epilogue only (barrier-separated)
    const int tid = threadIdx.x;
    const int lane = tid & 63;
    const int w = tid >> 6;
    const int i = lane & 15;
    const int q = lane >> 4;
    const int m0 = (m_off + blockIdx.x) * 64;

    // ---- phase 0: 4 slots x 2 head-pairs per node ----
    {
        const int r = tid >> 3, sub = tid & 7;
        const int hp = sub & 1;          // 0 -> heads {0,1}, 1 -> heads {2,3}
        const int slot = sub >> 1;       // 0..3 neighbor slot
        const int n = m0 + r;
        float acc[2][9] = {};
        float z[2] = {};
        const bool valid = (n < N_NODES);
        if (valid) {
            const float2 adv = *(const float2*)(ad4 + (size_t)n * 4 + hp * 2);
            int dg = deg[n];
            if (dg > CAP) dg = CAP;
#define GATHER1(SRC) do {                                                    \
            const f32x4* xp_ = (const f32x4*)(xa + (size_t)(SRC) * 16);      \
            f32x4 v0 = xp_[0], v1 = xp_[1], v2 = xp_[2], v3 = xp_[3];        \
            float as0 = hp ? v2.w : v2.y;                                    \
            float as1 = hp ? v3.x : v2.z;                                    \
            float e0 = __expf(lrelu(as0 + adv.x));                           \
            float e1 = __expf(lrelu(as1 + adv.y));                           \
            z[0] += e0; z[1] += e1;                                          \
            float xs[9] = {v0.x, v0.y, v0.z, v0.w, v1.x, v1.y, v1.z, v1.w, v2.x}; \
            _Pragma("unroll")                                                \
            for (int k = 0; k < 9; k++) {                                    \
                acc[0][k] += e0 * xs[k]; acc[1][k] += e1 * xs[k];            \
            }                                                                \
        } while (0)
            if (slot == 3) GATHER1(n);   // self loop (both head-pair lanes)
            int j = slot;
            int srcn = (j < dg) ? bucket[n * CAP + j] : -1;
            while (srcn >= 0) {          // bucket index prefetched one ahead
                int src = srcn;
                j += 4;
                srcn = (j < dg) ? bucket[n * CAP + j] : -1;
                GATHER1(src);
            }
#undef GATHER1
        }
        // 2-step butterfly over the 4 slot lanes (xor 2, xor 4; preserves hp bit)
#pragma unroll
        for (int off = 2; off <= 4; off <<= 1) {
#pragma unroll
            for (int h = 0; h < 2; h++) {
                z[h] += __shfl_xor(z[h], off);
#pragma unroll
                for (int k = 0; k < 9; k++) acc[h][k] += __shfl_xor(acc[h][k], off);
            }
        }
        if (sub < 2) {  // sub==0 writes heads 0,1; sub==1 writes heads 2,3
#pragma unroll
            for (int hh = 0; hh < 2; hh++) {
                float inv = valid ? 1.f / z[hh] : 0.f;
                f16x8 p0, p1;
#pragma unroll
                for (int k = 0; k < 8; k++) { p0[k] = (_Float16)(acc[hh][k] * inv); p1[k] = (_Float16)0.f; }
                p1[0] = (_Float16)(acc[hh][8] * inv);
                _Float16* dst = AgF + (size_t)((sub * 2 + hh) * 64 + r) * 24;
                *(f16x8*)dst = p0;
                *(f16x8*)(dst + 8) = p1;
            }
        }
    }
    __syncthreads();

    f32x4 acc[4];
#pragma unroll
    for (int r = 0; r < 4; r++) acc[r] = (f32x4){0.f, 0.f, 0.f, 0.f};

    const __bf16* bcol = wsB + (size_t)(w * 16 + i) * 512 + q * 8;
    const int nt = w & 1, jt = w >> 1;       // stage-A tile of this wave
    const int l31 = lane & 31, qh = lane >> 5;
    const int ilw = lane & 15, hw = (lane >> 4) & 1;

#pragma unroll
    for (int pass = 0; pass < 4; pass++) {
        bf16x8 breg[4];
#pragma unroll
        for (int kc = 0; kc < 4; kc++)
            breg[kc] = *(const bf16x8*)(bcol + pass * 128 + kc * 32);

        // ---- stage A: h2 cols [pass*128,+128) via 32x32x16 f16 MFMA ----
        {
            // A = W1^T tile: row j = jt*32+l31, k = qh*8+e
            f16x8 av = *(const f16x8*)(w1b + ((size_t)(pass * 128 + jt * 32 + l31) * 16 + qh * 8));
            // B = Ag tile: col node = nt*32+l31, k = qh*8+e
            f16x8 bv = *(const f16x8*)&AgF[(size_t)(pass * 64 + nt * 32 + l31) * 24 + qh * 8];
            f32x16 cfr = (f32x16){0.f, 0.f, 0.f, 0.f, 0.f, 0.f, 0.f, 0.f,
                                  0.f, 0.f, 0.f, 0.f, 0.f, 0.f, 0.f, 0.f};
            cfr = __builtin_amdgcn_mfma_f32_32x32x16_f16(av, bv, cfr, 0, 0, 0);
            // C: col = node = nt*32+l31; row = j = jt*32 + (reg&3) + 8*(reg>>2) + 4*qh
            // reg-quad r2 -> 4 consecutive j -> single b64 As write
#pragma unroll
            for (int r2 = 0; r2 < 4; r2++) {
                f32x4 b1v = *(const f32x4*)(b1 + pass * 128 + jt * 32 + r2 * 8 + qh * 4);
                bf16x4 pk;
#pragma unroll
                for (int m = 0; m < 4; m++) pk[m] = (__bf16)elu(cfr[r2 * 4 + m] + b1v[m]);
                *(bf16x4*)&As[(size_t)(((nt * 2 + hw) * 4 + jt) * 512 +
                                       (r2 * 16 + ilw) * 8 + qh * 4)] = pk;
            }
        }
        __syncthreads();

        // ---- phase 2: MFMA sweep over this pass's 4 kc-tiles ----
#pragma unroll
        for (int kc = 0; kc < 4; kc++) {
#pragma unroll
            for (int rt = 0; rt < 4; rt++) {
                bf16x8 af = *(const bf16x8*)&As[(rt * 4 + kc) * 512 + lane * 8];
                acc[rt] = __builtin_amdgcn_mfma_f32_16x16x32_bf16(af, breg[kc], acc[rt], 0, 0, 0);
            }
        }
        __syncthreads();
    }

    // ---- epilogue: p2b + asad2 via LDS cross-wave reduction ----
    float as2 = a_src2[w * 16 + i];
    float ad2 = a_dst2[w * 16 + i];
#pragma unroll
    for (int rt = 0; rt < 4; rt++) {
#pragma unroll
        for (int qq = 0; qq < 4; qq++) {
            int r2 = rt * 16 + q * 4 + qq;
            float v = acc[rt][qq];
            if (m0 + r2 < N_NODES)
                p2b[(size_t)(m0 + r2) * 128 + w * 16 + i] = (__bf16)v;
            float s = v * as2, d = v * ad2;
#pragma unroll
            for (int off = 1; off < 16; off <<= 1) {
                s += __shfl_xor(s, off);
                d += __shfl_xor(d, off);
            }
            if (i == 0) {
                red2[r2 * 16 + w * 2] = s;
                red2[r2 * 16 + w * 2 + 1] = d;
            }
        }
    }
    __syncthreads();
    if (tid < 128) {
        int r2 = tid >> 1, cc = tid & 1;
        float sum = 0.f;
#pragma unroll
        for (int ww = 0; ww < 8; ww++) sum += red2[r2 * 16 + ww * 2 + cc];
        if (m0 + r2 < N_NODES) asad2[(size_t)(m0 + r2) * 2 + cc] = sum;
    }
}

// Layer-2 attention + aggregation + elu + graph mean, fused:
// ONE BLOCK (4 waves) PER GRAPH; chunk-4 neighbor MLP gathers; LDS reduction.
__global__ __launch_bounds__(256) void k_agg2pool(
    const __bf16* __restrict__ p2b, const float* __restrict__ asad2,
    const int* __restrict__ deg, const int* __restrict__ bucket,
    const float* __restrict__ b2, const int* __restrict__ gstart,
    float* __restrict__ out) {
    __shared__ float red[4 * 128];
    int g = blockIdx.x;
    int tid = threadIdx.x;
    int wv = __builtin_amdgcn_readfirstlane(tid >> 6);
    int lane = tid & 63;
    int s0n = gstart[g], e0n = gstart[g + 1];
    float b2a = b2[2 * lane], b2b = b2[2 * lane + 1];
    float g0 = 0.f, g1 = 0.f;
    for (int n = s0n + wv; n < e0n; n += 4) {
        float ad = asad2[n * 2 + 1];
        float e = __expf(lrelu(asad2[n * 2] + ad));  // self loop
        float z = e;
        bf16x2 v = ((const bf16x2*)(p2b + (size_t)n * 128))[lane];
        float a0 = e * (float)v.x;
        float a1 = e * (float)v.y;
        int dg = deg[n];
        if (dg > CAP) dg = CAP;
        for (int j = 0; j < dg; j += 4) {
            int s0 = bucket[n * CAP + j];
            int s1 = bucket[n * CAP + min(j + 1, dg - 1)];
            int s2 = bucket[n * CAP + min(j + 2, dg - 1)];
            int s3 = bucket[n * CAP + min(j + 3, dg - 1)];
            float l0 = asad2[s0 * 2], l1 = asad2[s1 * 2];
            float l2 = asad2[s2 * 2], l3 = asad2[s3 * 2];
            bf16x2 w0 = ((const bf16x2*)(p2b + (size_t)s0 * 128))[lane];
            bf16x2 w1 = ((const bf16x2*)(p2b + (size_t)s1 * 128))[lane];
            bf16x2 w2 = ((const bf16x2*)(p2b + (size_t)s2 * 128))[lane];
            bf16x2 w3 = ((const bf16x2*)(p2b + (size_t)s3 * 128))[lane];
            float e0 = __expf(lrelu(l0 + ad));
            float e1 = (j + 1 < dg) ? __expf(lrelu(l1 + ad)) : 0.f;
            float e2 = (j + 2 < dg) ? __expf(lrelu(l2 + ad)) : 0.f;
            float e3 = (j + 3 < dg) ? __expf(lrelu(l3 + ad)) : 0.f;
            z += e0 + e1 + e2 + e3;
            a0 += e0 * (float)w0.x + e1 * (float)w1.x + e2 * (float)w2.x + e3 * (float)w3.x;
            a1 += e0 * (float)w0.y + e1 * (float)w1.y + e2 * (float)w2.y + e3 * (float)w3.y;
        }
        float inv = 1.f / z;
        g0 += elu(a0 * inv + b2a);
        g1 += elu(a1 * inv + b2b);
    }
    red[wv * 128 + 2 * lane] = g0;
    red[wv * 128 + 2 * lane + 1] = g1;
    __syncthreads();
    if (tid < 128) {
        float sum = red[tid] + red[128 + tid] + red[256 + tid] + red[384 + tid];
        int cnt = e0n - s0n;
        out[(size_t)g * 128 + tid] = sum / (float)(cnt > 0 ? cnt : 1);
    }
}

extern "C" void kernel_launch(void* const* d_in, const int* in_sizes, int n_in,
                              void* d_out, int out_size, void* d_ws, size_t ws_size,
                              hipStream_t stream) {
    const float* x       = (const float*)d_in[0];
    const int*   ei      = (const int*)d_in[1];
    const int*   batch   = (const int*)d_in[2];
    const float* W1      = (const float*)d_in[3];
    const float* a_src1  = (const float*)d_in[4];
    const float* a_dst1  = (const float*)d_in[5];
    const float* b1      = (const float*)d_in[6];
    const float* W2      = (const float*)d_in[7];
    const float* a_src2  = (const float*)d_in[8];
    const float* a_dst2  = (const float*)d_in[9];
    const float* b2      = (const float*)d_in[10];
    float* out = (float*)d_out;

    float* wsf   = (float*)d_ws;
    float* xa    = wsf + OFF_XA;
    float* ad4   = wsf + OFF_AD4;
    __bf16* p2b  = (__bf16*)(wsf + OFF_P2B);
    float* asad2 = wsf + OFF_ASAD2;
    __bf16* wsB  = (__bf16*)(wsf + OFF_WSB);
    _Float16* w1b = (_Float16*)(wsf + OFF_W1B);
    int* gstart  = (int*)(wsf + OFF_GST);
    int* wsi    = (int*)(wsf + OFF_INT);
    int* deg    = wsi;
    int* bucket = wsi + N_NODES;

    hipMemsetAsync(deg, 0, N_NODES * sizeof(int), stream);
    k_pre<<<PRE_BKT_END, 256, 0, stream>>>(x, W1, a_src1, a_dst1, W2, batch, ei,
                                           xa, ad4, wsB, w1b, deg, bucket, gstart);
    // 4-way chunked k_gemm (instrumentation: each dispatch ~18 us)
    for (int c = 0; c < 4; c++) {
        int off = c * GEMM_CHUNK;
        int blocks = (c == 3) ? (GEMM_BLOCKS - 3 * GEMM_CHUNK) : GEMM_CHUNK;
        k_gemm<<<blocks, 512, 0, stream>>>(xa, ad4, deg, bucket, w1b, b1,
                                           wsB, a_src2, a_dst2, p2b, asad2, off);
    }
    k_agg2pool<<<N_GRAPHS, 256, 0, stream>>>(p2b, asad2, deg, bucket, b2, gstart, out);
}

// Round 9
// 187.875 us; speedup vs baseline: 1.1818x; 1.1818x over previous
//
#include <hip/hip_runtime.h>

#define N_NODES 100000
#define N_EDGES 300000
#define N_GRAPHS 4000
#define CAP 32

typedef float f32x4 __attribute__((ext_vector_type(4)));
typedef float f32x16 __attribute__((ext_vector_type(16)));
typedef __bf16 bf16x8 __attribute__((ext_vector_type(8)));
typedef __bf16 bf16x4 __attribute__((ext_vector_type(4)));
typedef __bf16 bf16x2 __attribute__((ext_vector_type(2)));
typedef _Float16 f16x8 __attribute__((ext_vector_type(8)));

// ---------------- workspace layout (float offsets) ----------------
static const size_t OFF_XA    = 0;                                   // N*16
static const size_t OFF_AD4   = OFF_XA + (size_t)N_NODES * 16;       // N*4
static const size_t OFF_P2B   = OFF_AD4 + (size_t)N_NODES * 4;       // N*128 bf16
static const size_t OFF_ASAD2 = OFF_P2B + (size_t)N_NODES * 64;      // N*2
static const size_t OFF_WSB   = OFF_ASAD2 + (size_t)N_NODES * 2;     // 65536 bf16
static const size_t OFF_W1B   = OFF_WSB + 32768;                     // 8192 f16 = 4096 floats
static const size_t OFF_GST   = OFF_W1B + 4096;                      // gstart[4001]
static const size_t OFF_INT   = OFF_GST + 4096;                      // deg[N], bucket[N*CAP]

// k_pre block partition (256 threads each); deg zeroed by memset before launch
#define PRE_NODE_END 391   // ceil(100000/256)
#define PRE_PACKB_END 455  // +64: W2 pack
#define PRE_W1B_END 487    // +32: W1^T f16 pack [512][16]
#define PRE_GST_END 503    // +16: gstart
#define PRE_BKT_END 1675   // +1172: edge bucketing

__device__ __forceinline__ float lrelu(float x) { return x < 0.f ? 0.2f * x : x; }
__device__ __forceinline__ float elu(float x)   { return x > 0.f ? x : __expf(x) - 1.f; }

// Fat pre-kernel: node pack || W2 pack || W1^T pack || gstart || edge bucket
__global__ __launch_bounds__(256) void k_pre(
    const float* __restrict__ x, const float* __restrict__ W1,
    const float* __restrict__ a_src1, const float* __restrict__ a_dst1,
    const float* __restrict__ W2, const int* __restrict__ batch,
    const int* __restrict__ ei,
    float* __restrict__ xa, float* __restrict__ ad4,
    __bf16* __restrict__ wsB, _Float16* __restrict__ w1b,
    int* __restrict__ deg, int* __restrict__ bucket, int* __restrict__ gstart) {
    int b = blockIdx.x, tid = threadIdx.x;
    if (b < PRE_NODE_END) {
        __shared__ float wf[72];
        if (tid < 72) {
            int isd = tid / 36, r = tid % 36, k = r / 4, h = r % 4;
            const float* a = isd ? a_dst1 : a_src1;
            float s = 0.f;
            for (int c = 0; c < 128; c++) s += W1[k * 512 + h * 128 + c] * a[h * 128 + c];
            wf[tid] = s;
        }
        __syncthreads();
        int n = b * 256 + tid;
        if (n >= N_NODES) return;
        float xv[9];
#pragma unroll
        for (int k = 0; k < 9; k++) xv[k] = x[n * 9 + k];
        float as[4], ad[4];
#pragma unroll
        for (int h = 0; h < 4; h++) {
            float s = 0.f, d = 0.f;
#pragma unroll
            for (int k = 0; k < 9; k++) {
                s += xv[k] * wf[k * 4 + h];
                d += xv[k] * wf[36 + k * 4 + h];
            }
            as[h] = s; ad[h] = d;
        }
        f32x4* xp = (f32x4*)(xa + (size_t)n * 16);
        xp[0] = (f32x4){xv[0], xv[1], xv[2], xv[3]};
        xp[1] = (f32x4){xv[4], xv[5], xv[6], xv[7]};
        xp[2] = (f32x4){xv[8], as[0], as[1], as[2]};
        xp[3] = (f32x4){as[3], 0.f, 0.f, 0.f};
        *(f32x4*)(ad4 + (size_t)n * 4) = (f32x4){ad[0], ad[1], ad[2], ad[3]};
    } else if (b < PRE_PACKB_END) {
        int t = (b - PRE_NODE_END) * 256 + tid;
#pragma unroll
        for (int m = 0; m < 4; m++) {
            int idx = t * 4 + m;
            int k = idx >> 7, nn = idx & 127;
            wsB[(size_t)nn * 512 + k] = (__bf16)W2[(size_t)k * 128 + nn];
        }
    } else if (b < PRE_W1B_END) {
        int t = (b - PRE_PACKB_END) * 256 + tid;   // 0..8191
        int j = t >> 4, k = t & 15;
        w1b[t] = (k < 9) ? (_Float16)W1[(size_t)k * 512 + j] : (_Float16)0.f;
    } else if (b < PRE_GST_END) {
        int g = (b - PRE_W1B_END) * 256 + tid;
        if (g > N_GRAPHS) return;
        int lo = 0, hi = N_NODES;
        while (lo < hi) { int mid = (lo + hi) >> 1; if (batch[mid] < g) lo = mid + 1; else hi = mid; }
        gstart[g] = lo;
    } else {
        int e = (b - PRE_GST_END) * 256 + tid;
        if (e >= N_EDGES) return;
        int s = ei[e], d = ei[N_EDGES + e];
        int slot = atomicAdd(&deg[d], 1);
        if (slot < CAP) bucket[d * CAP + slot] = s;
    }
}

// Mega GEMM (r3 structure, best measured fused variant @69.5 us), single dispatch.
__global__ __launch_bounds__(512, 6) void k_gemm(
    const float* __restrict__ xa, const float* __restrict__ ad4,
    const int* __restrict__ deg, const int* __restrict__ bucket,
    const _Float16* __restrict__ w1b, const float* __restrict__ b1,
    const __bf16* __restrict__ wsB,
    const float* __restrict__ a_src2, const float* __restrict__ a_dst2,
    __bf16* __restrict__ p2b, float* __restrict__ asad2) {
    __shared__ __bf16 As[64 * 128];       // 16 KB, frag-major: tile t=rt*4+kc, lane*8
    __shared__ _Float16 AgF[4 * 64 * 24]; // 12 KB, [head][node][24] (k 0..15 used)
    float* red2 = (float*)AgF;            // 4 KB alias, epilogue only (barrier-separated)
    const int tid = threadIdx.x;
    const int lane = tid & 63;
    const int w = tid >> 6;
    const int i = lane & 15;
    const int q = lane >> 4;
    const int m0 = blockIdx.x * 64;

    // ---- phase 0: 4 slots x 2 head-pairs per node ----
    {
        const int r = tid >> 3, sub = tid & 7;
        const int hp = sub & 1;          // 0 -> heads {0,1}, 1 -> heads {2,3}
        const int slot = sub >> 1;       // 0..3 neighbor slot
        const int n = m0 + r;
        float acc[2][9] = {};
        float z[2] = {};
        const bool valid = (n < N_NODES);
        if (valid) {
            const float2 adv = *(const float2*)(ad4 + (size_t)n * 4 + hp * 2);
            int dg = deg[n];
            if (dg > CAP) dg = CAP;
#define GATHER1(SRC) do {                                                    \
            const f32x4* xp_ = (const f32x4*)(xa + (size_t)(SRC) * 16);      \
            f32x4 v0 = xp_[0], v1 = xp_[1], v2 = xp_[2], v3 = xp_[3];        \
            float as0 = hp ? v2.w : v2.y;                                    \
            float as1 = hp ? v3.x : v2.z;                                    \
            float e0 = __expf(lrelu(as0 + adv.x));                           \
            float e1 = __expf(lrelu(as1 + adv.y));                           \
            z[0] += e0; z[1] += e1;                                          \
            float xs[9] = {v0.x, v0.y, v0.z, v0.w, v1.x, v1.y, v1.z, v1.w, v2.x}; \
            _Pragma("unroll")                                                \
            for (int k = 0; k < 9; k++) {                                    \
                acc[0][k] += e0 * xs[k]; acc[1][k] += e1 * xs[k];            \
            }                                                                \
        } while (0)
            if (slot == 3) GATHER1(n);   // self loop (both head-pair lanes)
            int j = slot;
            int srcn = (j < dg) ? bucket[n * CAP + j] : -1;
            while (srcn >= 0) {          // bucket index prefetched one ahead
                int src = srcn;
                j += 4;
                srcn = (j < dg) ? bucket[n * CAP + j] : -1;
                GATHER1(src);
            }
#undef GATHER1
        }
        // 2-step butterfly over the 4 slot lanes (xor 2, xor 4; preserves hp bit)
#pragma unroll
        for (int off = 2; off <= 4; off <<= 1) {
#pragma unroll
            for (int h = 0; h < 2; h++) {
                z[h] += __shfl_xor(z[h], off);
#pragma unroll
                for (int k = 0; k < 9; k++) acc[h][k] += __shfl_xor(acc[h][k], off);
            }
        }
        if (sub < 2) {  // sub==0 writes heads 0,1; sub==1 writes heads 2,3
#pragma unroll
            for (int hh = 0; hh < 2; hh++) {
                float inv = valid ? 1.f / z[hh] : 0.f;
                f16x8 p0, p1;
#pragma unroll
                for (int k = 0; k < 8; k++) { p0[k] = (_Float16)(acc[hh][k] * inv); p1[k] = (_Float16)0.f; }
                p1[0] = (_Float16)(acc[hh][8] * inv);
                _Float16* dst = AgF + (size_t)((sub * 2 + hh) * 64 + r) * 24;
                *(f16x8*)dst = p0;
                *(f16x8*)(dst + 8) = p1;
            }
        }
    }
    __syncthreads();

    f32x4 acc[4];
#pragma unroll
    for (int r = 0; r < 4; r++) acc[r] = (f32x4){0.f, 0.f, 0.f, 0.f};

    const __bf16* bcol = wsB + (size_t)(w * 16 + i) * 512 + q * 8;
    const int nt = w & 1, jt = w >> 1;       // stage-A tile of this wave
    const int l31 = lane & 31, qh = lane >> 5;
    const int ilw = lane & 15, hw = (lane >> 4) & 1;

#pragma unroll
    for (int pass = 0; pass < 4; pass++) {
        bf16x8 breg[4];
#pragma unroll
        for (int kc = 0; kc < 4; kc++)
            breg[kc] = *(const bf16x8*)(bcol + pass * 128 + kc * 32);

        // ---- stage A: h2 cols [pass*128,+128) via 32x32x16 f16 MFMA ----
        {
            // A = W1^T tile: row j = jt*32+l31, k = qh*8+e
            f16x8 av = *(const f16x8*)(w1b + ((size_t)(pass * 128 + jt * 32 + l31) * 16 + qh * 8));
            // B = Ag tile: col node = nt*32+l31, k = qh*8+e
            f16x8 bv = *(const f16x8*)&AgF[(size_t)(pass * 64 + nt * 32 + l31) * 24 + qh * 8];
            f32x16 cfr = (f32x16){0.f, 0.f, 0.f, 0.f, 0.f, 0.f, 0.f, 0.f,
                                  0.f, 0.f, 0.f, 0.f, 0.f, 0.f, 0.f, 0.f};
            cfr = __builtin_amdgcn_mfma_f32_32x32x16_f16(av, bv, cfr, 0, 0, 0);
            // C: col = node = nt*32+l31; row = j = jt*32 + (reg&3) + 8*(reg>>2) + 4*qh
            // reg-quad r2 -> 4 consecutive j -> single b64 As write
#pragma unroll
            for (int r2 = 0; r2 < 4; r2++) {
                f32x4 b1v = *(const f32x4*)(b1 + pass * 128 + jt * 32 + r2 * 8 + qh * 4);
                bf16x4 pk;
#pragma unroll
                for (int m = 0; m < 4; m++) pk[m] = (__bf16)elu(cfr[r2 * 4 + m] + b1v[m]);
                *(bf16x4*)&As[(size_t)(((nt * 2 + hw) * 4 + jt) * 512 +
                                       (r2 * 16 + ilw) * 8 + qh * 4)] = pk;
            }
        }
        __syncthreads();

        // ---- phase 2: MFMA sweep over this pass's 4 kc-tiles ----
#pragma unroll
        for (int kc = 0; kc < 4; kc++) {
#pragma unroll
            for (int rt = 0; rt < 4; rt++) {
                bf16x8 af = *(const bf16x8*)&As[(rt * 4 + kc) * 512 + lane * 8];
                acc[rt] = __builtin_amdgcn_mfma_f32_16x16x32_bf16(af, breg[kc], acc[rt], 0, 0, 0);
            }
        }
        __syncthreads();
    }

    // ---- epilogue: p2b + asad2 via LDS cross-wave reduction ----
    float as2 = a_src2[w * 16 + i];
    float ad2 = a_dst2[w * 16 + i];
#pragma unroll
    for (int rt = 0; rt < 4; rt++) {
#pragma unroll
        for (int qq = 0; qq < 4; qq++) {
            int r2 = rt * 16 + q * 4 + qq;
            float v = acc[rt][qq];
            if (m0 + r2 < N_NODES)
                p2b[(size_t)(m0 + r2) * 128 + w * 16 + i] = (__bf16)v;
            float s = v * as2, d = v * ad2;
#pragma unroll
            for (int off = 1; off < 16; off <<= 1) {
                s += __shfl_xor(s, off);
                d += __shfl_xor(d, off);
            }
            if (i == 0) {
                red2[r2 * 16 + w * 2] = s;
                red2[r2 * 16 + w * 2 + 1] = d;
            }
        }
    }
    __syncthreads();
    if (tid < 128) {
        int r2 = tid >> 1, cc = tid & 1;
        float sum = 0.f;
#pragma unroll
        for (int ww = 0; ww < 8; ww++) sum += red2[r2 * 16 + ww * 2 + cc];
        if (m0 + r2 < N_NODES) asad2[(size_t)(m0 + r2) * 2 + cc] = sum;
    }
}

// Layer-2 attention + aggregation + elu + graph mean, fused.
// v2: TWO NODES IN FLIGHT per wave. The per-node cost is a 2-hop dependent
// chain (bucket -> {asad2[s] || 256B p2b[s] row}) whose rows were written
// dirty into other XCDs' L2 by k_gemm -> ~600-900cy per hop. Pairing nodes
// (n, n+4) issues both nodes' hop-1 loads, then all 16 hop-2 loads, then
// computes -> halves exposed latency. Poison-safe: bucket slots >= deg are
// clamped to a valid index BEFORE any dependent load (their weight is 0).
__global__ __launch_bounds__(256) void k_agg2pool(
    const __bf16* __restrict__ p2b, const float* __restrict__ asad2,
    const int* __restrict__ deg, const int* __restrict__ bucket,
    const float* __restrict__ b2, const int* __restrict__ gstart,
    float* __restrict__ out) {
    __shared__ float red[4 * 128];
    int g = blockIdx.x;
    int tid = threadIdx.x;
    int wv = __builtin_amdgcn_readfirstlane(tid >> 6);
    int lane = tid & 63;
    int s0n = gstart[g], e0n = gstart[g + 1];
    float b2a = b2[2 * lane], b2b = b2[2 * lane + 1];
    float g0 = 0.f, g1 = 0.f;
    for (int n = s0n + wv; n < e0n; n += 8) {
        const bool hb = (n + 4 < e0n);
        const int nb = hb ? n + 4 : n;
        // ---- hop 1: independent front-loads for BOTH nodes ----
        float lsA = asad2[n * 2],  adA = asad2[n * 2 + 1];
        float lsB = asad2[nb * 2], adB = asad2[nb * 2 + 1];
        int dgA = deg[n];  if (dgA > CAP) dgA = CAP;
        int dgB = hb ? deg[nb] : 0; if (dgB > CAP) dgB = CAP;
        bf16x2 vA = ((const bf16x2*)(p2b + (size_t)n  * 128))[lane];
        bf16x2 vB = ((const bf16x2*)(p2b + (size_t)nb * 128))[lane];
        int4 bkA = *(const int4*)(bucket + (size_t)n  * CAP);
        int4 bkB = *(const int4*)(bucket + (size_t)nb * CAP);
        // clamp poisoned slots (>= dg) to a known-valid node index
        int sA0 = (dgA > 0) ? bkA.x : n;
        int sA1 = (dgA > 1) ? bkA.y : sA0;
        int sA2 = (dgA > 2) ? bkA.z : sA0;
        int sA3 = (dgA > 3) ? bkA.w : sA0;
        int sB0 = (dgB > 0) ? bkB.x : nb;
        int sB1 = (dgB > 1) ? bkB.y : sB0;
        int sB2 = (dgB > 2) ? bkB.z : sB0;
        int sB3 = (dgB > 3) ? bkB.w : sB0;
        // ---- hop 2: all 16 dependent loads issued together ----
        float lA0 = asad2[sA0 * 2], lA1 = asad2[sA1 * 2];
        float lA2 = asad2[sA2 * 2], lA3 = asad2[sA3 * 2];
        float lB0 = asad2[sB0 * 2], lB1 = asad2[sB1 * 2];
        float lB2 = asad2[sB2 * 2], lB3 = asad2[sB3 * 2];
        bf16x2 wA0 = ((const bf16x2*)(p2b + (size_t)sA0 * 128))[lane];
        bf16x2 wA1 = ((const bf16x2*)(p2b + (size_t)sA1 * 128))[lane];
        bf16x2 wA2 = ((const bf16x2*)(p2b + (size_t)sA2 * 128))[lane];
        bf16x2 wA3 = ((const bf16x2*)(p2b + (size_t)sA3 * 128))[lane];
        bf16x2 wB0 = ((const bf16x2*)(p2b + (size_t)sB0 * 128))[lane];
        bf16x2 wB1 = ((const bf16x2*)(p2b + (size_t)sB1 * 128))[lane];
        bf16x2 wB2 = ((const bf16x2*)(p2b + (size_t)sB2 * 128))[lane];
        bf16x2 wB3 = ((const bf16x2*)(p2b + (size_t)sB3 * 128))[lane];
        // ---- compute node A ----
        {
            float e = __expf(lrelu(lsA + adA));  // self loop
            float z = e;
            float a0 = e * (float)vA.x, a1 = e * (float)vA.y;
            float e0 = (dgA > 0) ? __expf(lrelu(lA0 + adA)) : 0.f;
            float e1 = (dgA > 1) ? __expf(lrelu(lA1 + adA)) : 0.f;
            float e2 = (dgA > 2) ? __expf(lrelu(lA2 + adA)) : 0.f;
            float e3 = (dgA > 3) ? __expf(lrelu(lA3 + adA)) : 0.f;
            z += e0 + e1 + e2 + e3;
            a0 += e0 * (float)wA0.x + e1 * (float)wA1.x + e2 * (float)wA2.x + e3 * (float)wA3.x;
            a1 += e0 * (float)wA0.y + e1 * (float)wA1.y + e2 * (float)wA2.y + e3 * (float)wA3.y;
            for (int j = 4; j < dgA; j += 4) {   // rare deg>4 tail
                int s0 = bucket[n * CAP + j];
                int s1 = bucket[n * CAP + min(j + 1, dgA - 1)];
                int s2 = bucket[n * CAP + min(j + 2, dgA - 1)];
                int s3 = bucket[n * CAP + min(j + 3, dgA - 1)];
                float l0 = asad2[s0 * 2], l1 = asad2[s1 * 2];
                float l2 = asad2[s2 * 2], l3 = asad2[s3 * 2];
                bf16x2 w0 = ((const bf16x2*)(p2b + (size_t)s0 * 128))[lane];
                bf16x2 w1 = ((const bf16x2*)(p2b + (size_t)s1 * 128))[lane];
                bf16x2 w2 = ((const bf16x2*)(p2b + (size_t)s2 * 128))[lane];
                bf16x2 w3 = ((const bf16x2*)(p2b + (size_t)s3 * 128))[lane];
                float f0 = __expf(lrelu(l0 + adA));
                float f1 = (j + 1 < dgA) ? __expf(lrelu(l1 + adA)) : 0.f;
                float f2 = (j + 2 < dgA) ? __expf(lrelu(l2 + adA)) : 0.f;
                float f3 = (j + 3 < dgA) ? __expf(lrelu(l3 + adA)) : 0.f;
                z += f0 + f1 + f2 + f3;
                a0 += f0 * (float)w0.x + f1 * (float)w1.x + f2 * (float)w2.x + f3 * (float)w3.x;
                a1 += f0 * (float)w0.y + f1 * (float)w1.y + f2 * (float)w2.y + f3 * (float)w3.y;
            }
            float inv = 1.f / z;
            g0 += elu(a0 * inv + b2a);
            g1 += elu(a1 * inv + b2b);
        }
        // ---- compute node B ----
        if (hb) {
            float e = __expf(lrelu(lsB + adB));  // self loop
            float z = e;
            float a0 = e * (float)vB.x, a1 = e * (float)vB.y;
            float e0 = (dgB > 0) ? __expf(lrelu(lB0 + adB)) : 0.f;
            float e1 = (dgB > 1) ? __expf(lrelu(lB1 + adB)) : 0.f;
            float e2 = (dgB > 2) ? __expf(lrelu(lB2 + adB)) : 0.f;
            float e3 = (dgB > 3) ? __expf(lrelu(lB3 + adB)) : 0.f;
            z += e0 + e1 + e2 + e3;
            a0 += e0 * (float)wB0.x + e1 * (float)wB1.x + e2 * (float)wB2.x + e3 * (float)wB3.x;
            a1 += e0 * (float)wB0.y + e1 * (float)wB1.y + e2 * (float)wB2.y + e3 * (float)wB3.y;
            for (int j = 4; j < dgB; j += 4) {   // rare deg>4 tail
                int s0 = bucket[nb * CAP + j];
                int s1 = bucket[nb * CAP + min(j + 1, dgB - 1)];
                int s2 = bucket[nb * CAP + min(j + 2, dgB - 1)];
                int s3 = bucket[nb * CAP + min(j + 3, dgB - 1)];
                float l0 = asad2[s0 * 2], l1 = asad2[s1 * 2];
                float l2 = asad2[s2 * 2], l3 = asad2[s3 * 2];
                bf16x2 w0 = ((const bf16x2*)(p2b + (size_t)s0 * 128))[lane];
                bf16x2 w1 = ((const bf16x2*)(p2b + (size_t)s1 * 128))[lane];
                bf16x2 w2 = ((const bf16x2*)(p2b + (size_t)s2 * 128))[lane];
                bf16x2 w3 = ((const bf16x2*)(p2b + (size_t)s3 * 128))[lane];
                float f0 = __expf(lrelu(l0 + adB));
                float f1 = (j + 1 < dgB) ? __expf(lrelu(l1 + adB)) : 0.f;
                float f2 = (j + 2 < dgB) ? __expf(lrelu(l2 + adB)) : 0.f;
                float f3 = (j + 3 < dgB) ? __expf(lrelu(l3 + adB)) : 0.f;
                z += f0 + f1 + f2 + f3;
                a0 += f0 * (float)w0.x + f1 * (float)w1.x + f2 * (float)w2.x + f3 * (float)w3.x;
                a1 += f0 * (float)w0.y + f1 * (float)w1.y + f2 * (float)w2.y + f3 * (float)w3.y;
            }
            float inv = 1.f / z;
            g0 += elu(a0 * inv + b2a);
            g1 += elu(a1 * inv + b2b);
        }
    }
    red[wv * 128 + 2 * lane] = g0;
    red[wv * 128 + 2 * lane + 1] = g1;
    __syncthreads();
    if (tid < 128) {
        float sum = red[tid] + red[128 + tid] + red[256 + tid] + red[384 + tid];
        int cnt = e0n - s0n;
        out[(size_t)g * 128 + tid] = sum / (float)(cnt > 0 ? cnt : 1);
    }
}

extern "C" void kernel_launch(void* const* d_in, const int* in_sizes, int n_in,
                              void* d_out, int out_size, void* d_ws, size_t ws_size,
                              hipStream_t stream) {
    const float* x       = (const float*)d_in[0];
    const int*   ei      = (const int*)d_in[1];
    const int*   batch   = (const int*)d_in[2];
    const float* W1      = (const float*)d_in[3];
    const float* a_src1  = (const float*)d_in[4];
    const float* a_dst1  = (const float*)d_in[5];
    const float* b1      = (const float*)d_in[6];
    const float* W2      = (const float*)d_in[7];
    const float* a_src2  = (const float*)d_in[8];
    const float* a_dst2  = (const float*)d_in[9];
    const float* b2      = (const float*)d_in[10];
    float* out = (float*)d_out;

    float* wsf   = (float*)d_ws;
    float* xa    = wsf + OFF_XA;
    float* ad4   = wsf + OFF_AD4;
    __bf16* p2b  = (__bf16*)(wsf + OFF_P2B);
    float* asad2 = wsf + OFF_ASAD2;
    __bf16* wsB  = (__bf16*)(wsf + OFF_WSB);
    _Float16* w1b = (_Float16*)(wsf + OFF_W1B);
    int* gstart  = (int*)(wsf + OFF_GST);
    int* wsi    = (int*)(wsf + OFF_INT);
    int* deg    = wsi;
    int* bucket = wsi + N_NODES;

    hipMemsetAsync(deg, 0, N_NODES * sizeof(int), stream);
    k_pre<<<PRE_BKT_END, 256, 0, stream>>>(x, W1, a_src1, a_dst1, W2, batch, ei,
                                           xa, ad4, wsB, w1b, deg, bucket, gstart);
    k_gemm<<<(N_NODES + 63) / 64, 512, 0, stream>>>(xa, ad4, deg, bucket, w1b, b1,
                                                    wsB, a_src2, a_dst2, p2b, asad2);
    k_agg2pool<<<N_GRAPHS, 256, 0, stream>>>(p2b, asad2, deg, bucket, b2, gstart, out);
}